// Round 1
// baseline (2938.670 us; speedup 1.0000x reference)
//
#include <hip/hip_runtime.h>
#include <stdint.h>

#define NLOG 18
#define NPTS (1u << NLOG)
#define NMASK (NPTS - 1u)
#define DDIM 286u
#define RPB 64u
#define TPB 256u
#define RSTRIDE 288u  // 72 chunks of 4 floats; 288 % 32 == 0, swizzle handles banks

// ---- compile-time monomial table: nibble-packed (k0+1)|(k1+1)<<4|(k2+1)<<8 ----
struct Tab { uint16_t v[DDIM]; };

constexpr Tab make_tab() {
  Tab t{};
  int idx = 0;
  t.v[idx++] = 0;  // degree 0: constant 1
  for (int a = 0; a < 10; ++a) t.v[idx++] = (uint16_t)(a + 1);
  for (int a = 0; a < 10; ++a)
    for (int b = a; b < 10; ++b) t.v[idx++] = (uint16_t)((a + 1) | ((b + 1) << 4));
  for (int a = 0; a < 10; ++a)
    for (int b = a; b < 10; ++b)
      for (int c = b; c < 10; ++c)
        t.v[idx++] = (uint16_t)((a + 1) | ((b + 1) << 4) | ((c + 1) << 8));
  return t;
}
__constant__ Tab g_tab = make_tab();

// swizzled LDS offset: 16B chunk index XORed with (row & 7) -> conflict-free b128
__device__ __forceinline__ uint32_t swz(uint32_t row, uint32_t d) {
  uint32_t c = d >> 2;
  uint32_t cc = c ^ (row & 7u);
  return row * RSTRIDE + (cc << 2) + (d & 3u);
}

template <bool CD, bool CE>
__device__ __forceinline__ void tile_fma(const float* __restrict__ M,
                                         const float wd[8], const float we[8],
                                         uint32_t d0, uint32_t e0, float& acc) {
#pragma unroll
  for (uint32_t jj = 0; jj < 8; ++jj) {
    uint32_t ej = CE ? ((e0 + jj > 285u) ? 285u : (e0 + jj)) : (e0 + jj);
    float t = 0.f;
#pragma unroll
    for (uint32_t ii = 0; ii < 8; ++ii) {
      uint32_t di = CD ? ((d0 + ii > 285u) ? 285u : (d0 + ii)) : (d0 + ii);
      t = fmaf(wd[ii], M[di * DDIM + ej], t);
    }
    acc = fmaf(t, we[jj], acc);
  }
}

__global__ __launch_bounds__(TPB, 2) void qform_kernel(const float* __restrict__ x,
                                                       const float* __restrict__ M,
                                                       float* __restrict__ out) {
  __shared__ __align__(16) float w[RPB * RSTRIDE];
  __shared__ float partial[4][RPB];

  const uint32_t tid = threadIdx.x;
  const uint32_t n0 = blockIdx.x * RPB;
  const uint32_t base = n0 * DDIM;

  // zero the 2 pad floats per row (d = 286, 287)
  if (tid < RPB * 2u) {
    uint32_t row = tid >> 1, d = DDIM + (tid & 1u);
    w[swz(row, d)] = 0.f;
  }

  // cooperative staging: p -> (row, d); m = base + p -> (i = m>>18 monomial, j point)
  for (uint32_t p = tid; p < RPB * DDIM; p += TPB) {
    uint32_t m = base + p;
    uint32_t i = m >> NLOG;
    uint32_t j = m & NMASK;
    uint32_t tv = g_tab.v[i];
    float val = 1.0f;
    int a = (int)(tv & 15u) - 1;
    if (a >= 0) {
      val = x[((uint32_t)a << NLOG) + j];
      int b = (int)((tv >> 4) & 15u) - 1;
      if (b >= 0) {
        val *= x[((uint32_t)b << NLOG) + j];
        int c = (int)(tv >> 8) - 1;
        if (c >= 0) val *= x[((uint32_t)c << NLOG) + j];
      }
    }
    uint32_t row = p / DDIM;
    uint32_t d = p - row * DDIM;
    w[swz(row, d)] = val;
  }
  __syncthreads();

  // compute: lane = row; wave = e-range quarter (0..2: 72 e's, 3: 70 e's)
  const uint32_t wave = tid >> 6;
  const uint32_t lane = tid & 63u;
  const uint32_t s = lane & 7u;
  const float* wrow = &w[lane * RSTRIDE];
  const uint32_t e_begin = (uint32_t)__builtin_amdgcn_readfirstlane((int)(wave * 72u));
  float acc = 0.f;

#pragma unroll 1
  for (uint32_t a = 0; a < 36u; ++a) {
    float wd[8];
    {
      uint32_t c0 = (2u * a) ^ s, c1 = (2u * a + 1u) ^ s;
      const float4 lo = *(const float4*)&wrow[c0 << 2];
      const float4 hi = *(const float4*)&wrow[c1 << 2];
      wd[0] = lo.x; wd[1] = lo.y; wd[2] = lo.z; wd[3] = lo.w;
      wd[4] = hi.x; wd[5] = hi.y; wd[6] = hi.z; wd[7] = hi.w;
    }
    const uint32_t d0 = a * 8u;
    for (uint32_t b = 0; b < 9u; ++b) {
      uint32_t e0 = e_begin + b * 8u;
      float we[8];
      {
        uint32_t c0 = (e0 >> 2) ^ s, c1 = ((e0 >> 2) + 1u) ^ s;
        const float4 lo = *(const float4*)&wrow[c0 << 2];
        const float4 hi = *(const float4*)&wrow[c1 << 2];
        we[0] = lo.x; we[1] = lo.y; we[2] = lo.z; we[3] = lo.w;
        we[4] = hi.x; we[5] = hi.y; we[6] = hi.z; we[7] = hi.w;
      }
      const bool ce = (e0 == 280u);  // only wave 3, b == 8 reaches past 285
      if (a == 35u) {
        if (ce) tile_fma<true, true>(M, wd, we, d0, e0, acc);
        else    tile_fma<true, false>(M, wd, we, d0, e0, acc);
      } else {
        if (ce) tile_fma<false, true>(M, wd, we, d0, e0, acc);
        else    tile_fma<false, false>(M, wd, we, d0, e0, acc);
      }
    }
  }

  partial[wave][lane] = acc;
  __syncthreads();
  if (tid < RPB) {
    out[n0 + tid] = partial[0][tid] + partial[1][tid] + partial[2][tid] + partial[3][tid];
  }
}

extern "C" void kernel_launch(void* const* d_in, const int* in_sizes, int n_in,
                              void* d_out, int out_size, void* d_ws, size_t ws_size,
                              hipStream_t stream) {
  const float* x = (const float*)d_in[0];   // 262144*10 fp32, viewed as xr[10][262144]
  const float* M = (const float*)d_in[1];   // 286*286 fp32
  float* out = (float*)d_out;               // 262144 fp32
  (void)in_sizes; (void)n_in; (void)out_size; (void)d_ws; (void)ws_size;
  qform_kernel<<<dim3(NPTS / RPB), dim3(TPB), 0, stream>>>(x, M, out);
}

// Round 2
// 371.188 us; speedup vs baseline: 7.9169x; 7.9169x over previous
//
#include <hip/hip_runtime.h>
#include <stdint.h>

#define NLOG 18
#define NMASK ((1u << NLOG) - 1u)

typedef __attribute__((ext_vector_type(8))) short short8;
typedef __attribute__((ext_vector_type(4))) float f32x4;

// ---- compile-time monomial table: nibble-packed (a+1)|(b+1)<<4|(c+1)<<8 ----
struct Tab { uint16_t v[286]; };
constexpr Tab make_tab() {
  Tab t{};
  int idx = 0;
  t.v[idx++] = 0;  // degree 0
  for (int a = 0; a < 10; ++a) t.v[idx++] = (uint16_t)(a + 1);
  for (int a = 0; a < 10; ++a)
    for (int b = a; b < 10; ++b) t.v[idx++] = (uint16_t)((a + 1) | ((b + 1) << 4));
  for (int a = 0; a < 10; ++a)
    for (int b = a; b < 10; ++b)
      for (int c = b; c < 10; ++c)
        t.v[idx++] = (uint16_t)((a + 1) | ((b + 1) << 4) | ((c + 1) << 8));
  return t;
}
__constant__ Tab g_tab = make_tab();

// Packed bf16 B operand: 9 k-steps x 4 k-octets x 320 e, 16B chunk holds
// M[k0*32+g*8+i][e] for i=0..7.  9*4*320 = 11520 chunks = 184320 B.
__device__ uint4 g_bpack[11520];

__device__ __forceinline__ uint32_t f2bf(float f) {
  uint32_t u = __float_as_uint(f);
  return (u + 0x7FFFu + ((u >> 16) & 1u)) >> 16;
}
__device__ __forceinline__ float bf2f(uint32_t u) { return __uint_as_float(u << 16); }

__global__ __launch_bounds__(256) void prep_kernel(const float* __restrict__ M) {
  uint32_t t = blockIdx.x * 256u + threadIdx.x;  // 0..11519
  uint32_t k0 = t / 1280u;
  uint32_t r = t - k0 * 1280u;
  uint32_t g = r / 320u;
  uint32_t e = r - g * 320u;
  uint32_t kb = k0 * 32u + g * 8u;
  float v[8];
#pragma unroll
  for (int i = 0; i < 8; ++i) {
    uint32_t k = kb + (uint32_t)i;
    v[i] = (k < 286u && e < 286u) ? M[k * 286u + e] : 0.f;
  }
  uint4 o;
  o.x = f2bf(v[0]) | (f2bf(v[1]) << 16);
  o.y = f2bf(v[2]) | (f2bf(v[3]) << 16);
  o.z = f2bf(v[4]) | (f2bf(v[5]) << 16);
  o.w = f2bf(v[6]) | (f2bf(v[7]) << 16);
  g_bpack[t] = o;
}

__device__ __forceinline__ void gload16(const void* g, void* l) {
  __builtin_amdgcn_global_load_lds((const __attribute__((address_space(1))) uint32_t*)g,
                                   (__attribute__((address_space(3))) uint32_t*)l, 16, 0, 0);
}

// stage one 1280-chunk slab (20480 B) cooperatively: chunks tid, tid+512, tid+1024(<1280)
__device__ __forceinline__ void stage(const uint4* gs, uint4* ls, uint32_t tid) {
  gload16(gs + tid, ls + tid);
  gload16(gs + tid + 512u, ls + tid + 512u);
  if (tid < 256u) gload16(gs + tid + 1024u, ls + tid + 1024u);
}

// LDS map: W tile chunk-index = row*40 + swz(chunk,row); swz XORs low3 of chunk with row&7
__device__ __forceinline__ uint32_t cswz(uint32_t ch, uint32_t row) {
  return (ch & ~7u) | ((ch & 7u) ^ (row & 7u));
}

__global__ __launch_bounds__(512, 1) void qform_kernel(const float* __restrict__ x,
                                                       float* __restrict__ out) {
  extern __shared__ char smem[];                       // layout:
  uint4* wb = (uint4*)smem;                            // [0, 81920): W 128 rows x 40 chunks
  uint4* bst0 = (uint4*)(smem + 81920);                // [81920, 102400): B buf 0
  uint4* bst1 = (uint4*)(smem + 102400);               // [102400,122880): B buf 1
  float* part = (float*)(smem + 122880);               // [122880,124928): 4x128 f32

  const uint32_t tid = threadIdx.x;
  const uint32_t wid = tid >> 6, lane = tid & 63u;
  const uint32_t n0 = blockIdx.x * 128u;
  const uint32_t mb = blockIdx.x * 36608u;  // 128*286

  // ---- stage B slab 0 early (hide latency under W-gen)
  stage(g_bpack, bst0, tid);

  // ---- zero pad region of W: chunks 36..39 all rows, chunk 35 bytes 12..15 (d=286,287)
  {
    uint32_t r = tid >> 2;
    uint32_t pc = 36u + (tid & 3u);
    uint4 z; z.x = 0; z.y = 0; z.z = 0; z.w = 0;
    wb[r * 40u + cswz(pc, r)] = z;
  }
  if (tid < 128u) {
    uint32_t r = tid;
    *(uint32_t*)(smem + (r * 40u + cswz(35u, r)) * 16u + 12u) = 0u;
  }

  // ---- W-gen: stream element m = mb+p, p in [0,36608); w[row][d] with row=p/286, d=p%286
  for (uint32_t g = 0; g < 9u; ++g) {
    uint32_t t8 = g * 512u + tid;
    if (t8 >= 4576u) break;
    uint32_t p0 = t8 * 8u;
    uint32_t m0 = mb + p0;
    uint32_t row0 = p0 / 286u;
    uint32_t d0 = p0 - row0 * 286u;  // even
    bool slow = (d0 > 278u) || ((m0 >> NLOG) != ((m0 + 7u) >> NLOG));
    if (!slow) {
      uint32_t i = m0 >> NLOG, j0 = m0 & NMASK;  // j0 multiple of 8 -> aligned float4
      uint32_t tv = g_tab.v[i];
      float pr[8];
      int a = (int)(tv & 15u) - 1;
      if (a >= 0) {
        const float4* xa = (const float4*)(x + ((uint32_t)a << NLOG) + j0);
        float4 lo = xa[0], hi = xa[1];
        pr[0] = lo.x; pr[1] = lo.y; pr[2] = lo.z; pr[3] = lo.w;
        pr[4] = hi.x; pr[5] = hi.y; pr[6] = hi.z; pr[7] = hi.w;
        int b = (int)((tv >> 4) & 15u) - 1;
        if (b >= 0) {
          const float4* xb = (const float4*)(x + ((uint32_t)b << NLOG) + j0);
          float4 lo2 = xb[0], hi2 = xb[1];
          pr[0] *= lo2.x; pr[1] *= lo2.y; pr[2] *= lo2.z; pr[3] *= lo2.w;
          pr[4] *= hi2.x; pr[5] *= hi2.y; pr[6] *= hi2.z; pr[7] *= hi2.w;
          int c = (int)(tv >> 8) - 1;
          if (c >= 0) {
            const float4* xc = (const float4*)(x + ((uint32_t)c << NLOG) + j0);
            float4 lo3 = xc[0], hi3 = xc[1];
            pr[0] *= lo3.x; pr[1] *= lo3.y; pr[2] *= lo3.z; pr[3] *= lo3.w;
            pr[4] *= hi3.x; pr[5] *= hi3.y; pr[6] *= hi3.z; pr[7] *= hi3.w;
          }
        }
      } else {
#pragma unroll
        for (int u = 0; u < 8; ++u) pr[u] = 1.f;
      }
#pragma unroll
      for (uint32_t u = 0; u < 4u; ++u) {
        uint32_t d = d0 + 2u * u;
        uint32_t pk = f2bf(pr[2 * u]) | (f2bf(pr[2 * u + 1]) << 16);
        *(uint32_t*)(smem + (row0 * 40u + cswz(d >> 3, row0)) * 16u + (d & 7u) * 2u) = pk;
      }
    } else {
#pragma unroll
      for (uint32_t u = 0; u < 8u; ++u) {
        uint32_t p = p0 + u, m = m0 + u;
        uint32_t i = m >> NLOG, j = m & NMASK;
        uint32_t tv = g_tab.v[i];
        float val = 1.f;
        int a = (int)(tv & 15u) - 1;
        if (a >= 0) {
          val = x[((uint32_t)a << NLOG) + j];
          int b = (int)((tv >> 4) & 15u) - 1;
          if (b >= 0) {
            val *= x[((uint32_t)b << NLOG) + j];
            int c = (int)(tv >> 8) - 1;
            if (c >= 0) val *= x[((uint32_t)c << NLOG) + j];
          }
        }
        uint32_t row = p / 286u, d = p - row * 286u;
        *(uint16_t*)(smem + (row * 40u + cswz(d >> 3, row)) * 16u + (d & 7u) * 2u) =
            (uint16_t)f2bf(val);
      }
    }
  }
  __syncthreads();

  // ---- GEMM main loop: wave (wr,we): rows wr*64..+64, e-cols we*80..+80
  const uint32_t wr = wid >> 2, we = wid & 3u;
  const uint32_t ag = lane >> 4;          // k-octet group
  const uint32_t al = lane & 15u;         // row-in-frag / col-in-frag
  f32x4 acc[4][5];
#pragma unroll
  for (int rf = 0; rf < 4; ++rf)
#pragma unroll
    for (int fe = 0; fe < 5; ++fe) acc[rf][fe] = (f32x4){0.f, 0.f, 0.f, 0.f};

  const uint4* bc = bst0;
  uint4* bn = bst1;
#pragma unroll 1
  for (int k0 = 0; k0 < 9; ++k0) {
    if (k0 < 8) stage(g_bpack + (k0 + 1) * 1280, bn, tid);
    short8 a[4], b[5];
#pragma unroll
    for (uint32_t rf = 0; rf < 4u; ++rf) {
      uint32_t r = wr * 64u + rf * 16u + al;
      uint32_t c = (uint32_t)k0 * 4u + ag;
      a[rf] = *(const short8*)(smem + (r * 40u + cswz(c, r)) * 16u);
    }
#pragma unroll
    for (uint32_t fe = 0; fe < 5u; ++fe)
      b[fe] = *(const short8*)(bc + ag * 320u + (we * 5u + fe) * 16u + al);
#pragma unroll
    for (int rf = 0; rf < 4; ++rf)
#pragma unroll
      for (int fe = 0; fe < 5; ++fe)
        acc[rf][fe] = __builtin_amdgcn_mfma_f32_16x16x32_bf16(a[rf], b[fe], acc[rf][fe], 0, 0, 0);
    __syncthreads();
    uint4* tmp = (uint4*)bc; bc = (const uint4*)bn; bn = tmp;
  }

  // ---- epilogue: out-frag rows r=(lane>>4)*4+i, col e=lane&15 (+16*fe +80*we)
  float rs[4][4];
#pragma unroll
  for (uint32_t rf = 0; rf < 4u; ++rf) {
#pragma unroll
    for (uint32_t i = 0; i < 4u; ++i) {
      uint32_t r = wr * 64u + rf * 16u + ag * 4u + i;
      float s = 0.f;
#pragma unroll
      for (uint32_t fe = 0; fe < 5u; ++fe) {
        uint32_t e = we * 80u + fe * 16u + al;
        float wv = bf2f(*(const uint16_t*)(smem + (r * 40u + cswz(e >> 3, r)) * 16u + (e & 7u) * 2u));
        s = fmaf(acc[rf][fe][i], wv, s);
      }
      rs[rf][i] = s;
    }
  }
#pragma unroll
  for (uint32_t rf = 0; rf < 4u; ++rf)
#pragma unroll
    for (uint32_t i = 0; i < 4u; ++i) {
      float s = rs[rf][i];
      s += __shfl_xor(s, 1); s += __shfl_xor(s, 2);
      s += __shfl_xor(s, 4); s += __shfl_xor(s, 8);
      rs[rf][i] = s;
    }
  if (al == 0u) {
#pragma unroll
    for (uint32_t rf = 0; rf < 4u; ++rf)
#pragma unroll
      for (uint32_t i = 0; i < 4u; ++i)
        part[we * 128u + wr * 64u + rf * 16u + ag * 4u + i] = rs[rf][i];
  }
  __syncthreads();
  if (tid < 128u) {
    out[n0 + tid] = part[tid] + part[128u + tid] + part[256u + tid] + part[384u + tid];
  }
}

extern "C" void kernel_launch(void* const* d_in, const int* in_sizes, int n_in,
                              void* d_out, int out_size, void* d_ws, size_t ws_size,
                              hipStream_t stream) {
  const float* x = (const float*)d_in[0];   // 262144*10 fp32, viewed as xr[10][262144]
  const float* M = (const float*)d_in[1];   // 286*286 fp32
  float* out = (float*)d_out;               // 262144 fp32
  (void)in_sizes; (void)n_in; (void)out_size; (void)d_ws; (void)ws_size;
  prep_kernel<<<45, 256, 0, stream>>>(M);
  hipFuncSetAttribute((const void*)qform_kernel, hipFuncAttributeMaxDynamicSharedMemorySize,
                      124928);
  qform_kernel<<<2048, 512, 124928, stream>>>(x, out);
}

// Round 4
// 320.795 us; speedup vs baseline: 9.1606x; 1.1571x over previous
//
#include <hip/hip_runtime.h>
#include <stdint.h>

#define NLOG 18
#define NMASK ((1u << NLOG) - 1u)
#define RSTRB 592u  // W row stride in bytes = 37 chunks * 16B; 148 dwords == 20 mod 32 banks

typedef __attribute__((ext_vector_type(8))) short short8;
typedef __attribute__((ext_vector_type(4))) float f32x4;

// ---- compile-time monomial table: nibble-packed (a+1)|(b+1)<<4|(c+1)<<8 ----
struct Tab { uint16_t v[286]; };
constexpr Tab make_tab() {
  Tab t{};
  int idx = 0;
  t.v[idx++] = 0;  // degree 0
  for (int a = 0; a < 10; ++a) t.v[idx++] = (uint16_t)(a + 1);
  for (int a = 0; a < 10; ++a)
    for (int b = a; b < 10; ++b) t.v[idx++] = (uint16_t)((a + 1) | ((b + 1) << 4));
  for (int a = 0; a < 10; ++a)
    for (int b = a; b < 10; ++b)
      for (int c = b; c < 10; ++c)
        t.v[idx++] = (uint16_t)((a + 1) | ((b + 1) << 4) | ((c + 1) << 8));
  return t;
}
__constant__ Tab g_tab = make_tab();

// Packed bf16 B operand: 9 k-steps x 4 k-octets x 320 e; 16B chunk = M[k0*32+g*8+i][e], i=0..7
// 9*4*320 = 11520 chunks = 184 KB; L2-resident on every XCD -> read directly, no LDS staging.
__device__ uint4 g_bpack[11520];

__device__ __forceinline__ uint32_t f2bf(float f) {
  uint32_t u = __float_as_uint(f);
  return (u + 0x7FFFu + ((u >> 16) & 1u)) >> 16;
}
__device__ __forceinline__ float bf2f(uint32_t u) { return __uint_as_float(u << 16); }

__global__ __launch_bounds__(256) void prep_kernel(const float* __restrict__ M) {
  uint32_t t = blockIdx.x * 256u + threadIdx.x;  // 0..11519
  uint32_t k0 = t / 1280u;
  uint32_t r = t - k0 * 1280u;
  uint32_t g = r / 320u;
  uint32_t e = r - g * 320u;
  uint32_t kb = k0 * 32u + g * 8u;
  float v[8];
#pragma unroll
  for (int i = 0; i < 8; ++i) {
    uint32_t k = kb + (uint32_t)i;
    v[i] = (k < 286u && e < 286u) ? M[k * 286u + e] : 0.f;
  }
  uint4 o;
  o.x = f2bf(v[0]) | (f2bf(v[1]) << 16);
  o.y = f2bf(v[2]) | (f2bf(v[3]) << 16);
  o.z = f2bf(v[4]) | (f2bf(v[5]) << 16);
  o.w = f2bf(v[6]) | (f2bf(v[7]) << 16);
  g_bpack[t] = o;
}

__global__ __launch_bounds__(512, 4) void qform_kernel(const float* __restrict__ x,
                                                       float* __restrict__ out) {
  extern __shared__ char smem[];            // [0,75776): W 128 rows x 37 chunks (592 B stride)
  float* part = (float*)(smem + 75776);     // [75776,77824): 4 x 128 f32 partials

  const uint32_t tid = threadIdx.x;
  const uint32_t wid = tid >> 6, lane = tid & 63u;
  const uint32_t n0 = blockIdx.x * 128u;
  const uint32_t mb = blockIdx.x * 36608u;  // 128*286

  // zero W pad elements d=286,287 per row (A pad must be real zeros: 0*garbage may be NaN)
  if (tid < 128u) *(uint32_t*)(smem + tid * RSTRB + 572u) = 0u;

  // ---- W-gen: element m = mb+p, p in [0,36608); w[row][d], row=p/286, d=p%286.
  // Within a row, monomial index i = m>>18 is constant and j = m&mask consecutive ->
  // 8-wide vectorized fast path except at row/i boundaries.
  for (uint32_t g = 0; g < 9u; ++g) {
    uint32_t t8 = g * 512u + tid;
    if (t8 >= 4576u) break;
    uint32_t p0 = t8 * 8u;
    uint32_t m0 = mb + p0;
    uint32_t row0 = p0 / 286u;
    uint32_t d0 = p0 - row0 * 286u;  // even
    bool slow = (d0 > 278u) || ((m0 >> NLOG) != ((m0 + 7u) >> NLOG));
    if (!slow) {
      uint32_t i = m0 >> NLOG, j0 = m0 & NMASK;  // j0 multiple of 8 -> aligned float4
      uint32_t tv = g_tab.v[i];
      float pr[8];
      int a = (int)(tv & 15u) - 1;
      if (a >= 0) {
        const float4* xa = (const float4*)(x + ((uint32_t)a << NLOG) + j0);
        float4 lo = xa[0], hi = xa[1];
        pr[0] = lo.x; pr[1] = lo.y; pr[2] = lo.z; pr[3] = lo.w;
        pr[4] = hi.x; pr[5] = hi.y; pr[6] = hi.z; pr[7] = hi.w;
        int b = (int)((tv >> 4) & 15u) - 1;
        if (b >= 0) {
          const float4* xb = (const float4*)(x + ((uint32_t)b << NLOG) + j0);
          float4 lo2 = xb[0], hi2 = xb[1];
          pr[0] *= lo2.x; pr[1] *= lo2.y; pr[2] *= lo2.z; pr[3] *= lo2.w;
          pr[4] *= hi2.x; pr[5] *= hi2.y; pr[6] *= hi2.z; pr[7] *= hi2.w;
          int c = (int)(tv >> 8) - 1;
          if (c >= 0) {
            const float4* xc = (const float4*)(x + ((uint32_t)c << NLOG) + j0);
            float4 lo3 = xc[0], hi3 = xc[1];
            pr[0] *= lo3.x; pr[1] *= lo3.y; pr[2] *= lo3.z; pr[3] *= lo3.w;
            pr[4] *= hi3.x; pr[5] *= hi3.y; pr[6] *= hi3.z; pr[7] *= hi3.w;
          }
        }
      } else {
#pragma unroll
        for (int u = 0; u < 8; ++u) pr[u] = 1.f;
      }
#pragma unroll
      for (uint32_t u = 0; u < 4u; ++u) {
        uint32_t d = d0 + 2u * u;
        uint32_t pk = f2bf(pr[2 * u]) | (f2bf(pr[2 * u + 1]) << 16);
        *(uint32_t*)(smem + row0 * RSTRB + d * 2u) = pk;
      }
    } else {
#pragma unroll
      for (uint32_t u = 0; u < 8u; ++u) {
        uint32_t p = p0 + u, m = m0 + u;
        uint32_t i = m >> NLOG, j = m & NMASK;
        uint32_t tv = g_tab.v[i];
        float val = 1.f;
        int a = (int)(tv & 15u) - 1;
        if (a >= 0) {
          val = x[((uint32_t)a << NLOG) + j];
          int b = (int)((tv >> 4) & 15u) - 1;
          if (b >= 0) {
            val *= x[((uint32_t)b << NLOG) + j];
            int c = (int)(tv >> 8) - 1;
            if (c >= 0) val *= x[((uint32_t)c << NLOG) + j];
          }
        }
        uint32_t row = p / 286u, d = p - row * 286u;
        *(uint16_t*)(smem + row * RSTRB + d * 2u) = (uint16_t)f2bf(val);
      }
    }
  }
  __syncthreads();

  // ---- GEMM: wave (wr,we): rows wr*64..+64, e-cols we*80..+80. No barriers in k-loop:
  // A from LDS (conflict-free via stride-37), B from global (L2-resident 184 KB).
  const uint32_t wr = wid >> 2, we = wid & 3u;
  const uint32_t ag = lane >> 4;   // k-octet group
  const uint32_t al = lane & 15u;  // row-in-frag / col-in-frag
  f32x4 acc[4][5];
#pragma unroll
  for (int rf = 0; rf < 4; ++rf)
#pragma unroll
    for (int fe = 0; fe < 5; ++fe) acc[rf][fe] = (f32x4){0.f, 0.f, 0.f, 0.f};

  const uint4* bbase = g_bpack + ag * 320u + we * 80u + al;
#pragma unroll 1
  for (uint32_t k0 = 0; k0 < 9u; ++k0) {
    short8 a[4], b[5];
#pragma unroll
    for (uint32_t rf = 0; rf < 4u; ++rf)
      a[rf] = *(const short8*)(smem + (wr * 64u + rf * 16u + al) * RSTRB + (k0 * 4u + ag) * 16u);
#pragma unroll
    for (uint32_t fe = 0; fe < 5u; ++fe)
      b[fe] = *(const short8*)(bbase + k0 * 1280u + fe * 16u);
#pragma unroll
    for (int rf = 0; rf < 4; ++rf)
#pragma unroll
      for (int fe = 0; fe < 5; ++fe)
        acc[rf][fe] = __builtin_amdgcn_mfma_f32_16x16x32_bf16(a[rf], b[fe], acc[rf][fe], 0, 0, 0);
  }

  // ---- epilogue: C-frag rows r=(lane>>4)*4+i, col e=al (+16*fe +80*we); dot with w-row.
  // CLAMP e<288: acc is exactly 0 for e>=286 (B cols zeroed), but the LDS bytes past
  // d=287 are uninitialized -> 0*NaN = NaN. d=286,287 are zeroed so e<288 loads are safe.
  float rs[4][4];
#pragma unroll
  for (uint32_t rf = 0; rf < 4u; ++rf) {
#pragma unroll
    for (uint32_t i = 0; i < 4u; ++i) {
      uint32_t r = wr * 64u + rf * 16u + ag * 4u + i;
      float s = 0.f;
#pragma unroll
      for (uint32_t fe = 0; fe < 5u; ++fe) {
        uint32_t e = we * 80u + fe * 16u + al;
        float wv = (e < 288u)
            ? bf2f(*(const uint16_t*)(smem + r * RSTRB + e * 2u))
            : 0.f;
        s = fmaf(acc[rf][fe][i], wv, s);
      }
      rs[rf][i] = s;
    }
  }
#pragma unroll
  for (uint32_t rf = 0; rf < 4u; ++rf)
#pragma unroll
    for (uint32_t i = 0; i < 4u; ++i) {
      float s = rs[rf][i];
      s += __shfl_xor(s, 1); s += __shfl_xor(s, 2);
      s += __shfl_xor(s, 4); s += __shfl_xor(s, 8);
      rs[rf][i] = s;
    }
  if (al == 0u) {
#pragma unroll
    for (uint32_t rf = 0; rf < 4u; ++rf)
#pragma unroll
      for (uint32_t i = 0; i < 4u; ++i)
        part[we * 128u + wr * 64u + rf * 16u + ag * 4u + i] = rs[rf][i];
  }
  __syncthreads();
  if (tid < 128u) {
    out[n0 + tid] = part[tid] + part[128u + tid] + part[256u + tid] + part[384u + tid];
  }
}

extern "C" void kernel_launch(void* const* d_in, const int* in_sizes, int n_in,
                              void* d_out, int out_size, void* d_ws, size_t ws_size,
                              hipStream_t stream) {
  const float* x = (const float*)d_in[0];   // 262144*10 fp32, viewed as xr[10][262144]
  const float* M = (const float*)d_in[1];   // 286*286 fp32
  float* out = (float*)d_out;               // 262144 fp32
  (void)in_sizes; (void)n_in; (void)out_size; (void)d_ws; (void)ws_size;
  prep_kernel<<<45, 256, 0, stream>>>(M);
  hipFuncSetAttribute((const void*)qform_kernel, hipFuncAttributeMaxDynamicSharedMemorySize,
                      77824);
  qform_kernel<<<2048, 512, 77824, stream>>>(x, out);
}